// Round 5
// baseline (159.407 us; speedup 1.0000x reference)
//
#include <hip/hip_runtime.h>
#include <math.h>

#define B_ 4
#define S_ 4096
#define H_ 1024
#define NH 16
#define DH 64
#define CTX 128
#define CSTART (S_ - CTX)   // 3968
#define KDIM 1024

typedef __attribute__((ext_vector_type(8))) short short8;
typedef __attribute__((ext_vector_type(4))) float floatx4;
typedef unsigned short ushort_t;

__device__ inline unsigned short f2bf(float x) {
    union { float f; unsigned u; } v; v.f = x;
    unsigned r = v.u + 0x7fffu + ((v.u >> 16) & 1u);   // RNE
    return (unsigned short)(r >> 16);
}

__device__ inline uint4 pack8(float4 a, float4 b) {
    union { unsigned short us[8]; uint4 u4; } p;
    p.us[0]=f2bf(a.x); p.us[1]=f2bf(a.y); p.us[2]=f2bf(a.z); p.us[3]=f2bf(a.w);
    p.us[4]=f2bf(b.x); p.us[5]=f2bf(b.y); p.us[6]=f2bf(b.z); p.us[7]=f2bf(b.w);
    return p.u4;
}

#define GLOAD_LDS16(g, l) \
    __builtin_amdgcn_global_load_lds((__attribute__((address_space(1))) const void*)(g), \
                                     (__attribute__((address_space(3))) void*)(l), 16, 0, 0)

// ---------- prep: conv weights (blocks 0..2047) + gather x slice (2048..2303) ----------
__global__ __launch_bounds__(256) void prep(const float* __restrict__ in,
                                            const float* __restrict__ Wq, const float* __restrict__ Wk,
                                            const float* __restrict__ Wv, const float* __restrict__ Wo,
                                            ushort_t* __restrict__ Wbf, ushort_t* __restrict__ Xs) {
    int bx = blockIdx.x;
    if (bx < 2048) {
        size_t idx = (size_t)bx * 256 + threadIdx.x;
        size_t e = idx * 8;
        int wsel = (int)(e >> 20);
        size_t off = e & 1048575;
        const float* src = wsel == 0 ? Wq : wsel == 1 ? Wk : wsel == 2 ? Wv : Wo;
        const float4* s4 = (const float4*)(src + off);
        *(uint4*)(Wbf + e) = pack8(s4[0], s4[1]);
    } else {
        int idx = (bx - 2048) * 256 + threadIdx.x;
        int e = idx * 8;
        int m = e >> 10;
        int col = e & 1023;
        int b = m >> 7, i = m & 127;
        const float4* s4 = (const float4*)(in + (size_t)(b * S_ + CSTART + i) * H_ + col);
        *(uint4*)(Xs + e) = pack8(s4[0], s4[1]);
    }
}

// ---------- bf16 MFMA GEMM, BK=64, double-buffered LDS (ONE barrier per K-iter) ----------
// MODE 0: store fp32 to C (ldc).  MODE 1: store bf16 to C (ldc).
// MODE 2: store fp32 rows to out (last-128 layout) + capture p==0 rows into rbuf.
template<int MODE>
__global__ __launch_bounds__(256) void gemm_t(const ushort_t* __restrict__ A,
                                              const ushort_t* __restrict__ W,
                                              void* __restrict__ Cv,
                                              float* __restrict__ rbuf, int ldc) {
    __shared__ ushort_t As[2][4096];
    __shared__ ushort_t Bs[2][4096];
    int tid = threadIdx.x;
    int lane = tid & 63, w = tid >> 6;
    int m0 = blockIdx.y * 64, n0 = blockIdx.x * 64;
    int f0 = tid, f1 = tid + 256;
    int r0 = f0 >> 3, g0 = (f0 & 7) ^ (r0 & 7);
    int r1 = f1 >> 3, g1 = (f1 & 7) ^ (r1 & 7);
    const ushort_t* ga0 = A + (size_t)(m0 + r0) * KDIM + g0 * 8;
    const ushort_t* ga1 = A + (size_t)(m0 + r1) * KDIM + g1 * 8;
    const ushort_t* gb0 = W + (size_t)(n0 + r0) * KDIM + g0 * 8;
    const ushort_t* gb1 = W + (size_t)(n0 + r1) * KDIM + g1 * 8;
    char* la0[2] = { (char*)&As[0][0] + f0 * 16, (char*)&As[1][0] + f0 * 16 };
    char* la1[2] = { (char*)&As[0][0] + f1 * 16, (char*)&As[1][0] + f1 * 16 };
    char* lb0[2] = { (char*)&Bs[0][0] + f0 * 16, (char*)&Bs[1][0] + f0 * 16 };
    char* lb1[2] = { (char*)&Bs[0][0] + f1 * 16, (char*)&Bs[1][0] + f1 * 16 };
    int fm = lane & 15, q = lane >> 4;
    int wr = w >> 1, wc = w & 1;
    int ma0 = wr * 32, na0 = wc * 32;
    floatx4 acc[2][2] = {};
    // prologue: tile 0 -> buf 0
    GLOAD_LDS16(ga0, la0[0]);
    GLOAD_LDS16(ga1, la1[0]);
    GLOAD_LDS16(gb0, lb0[0]);
    GLOAD_LDS16(gb1, lb1[0]);
    for (int it = 0; it < KDIM / 64; it++) {
        __syncthreads();                    // drains vmcnt -> tile `it` resident
        int buf = it & 1;
        if (it + 1 < KDIM / 64) {           // prefetch tile it+1 into other buffer
            int ko = (it + 1) * 64;
            GLOAD_LDS16(ga0 + ko, la0[buf ^ 1]);
            GLOAD_LDS16(ga1 + ko, la1[buf ^ 1]);
            GLOAD_LDS16(gb0 + ko, lb0[buf ^ 1]);
            GLOAD_LDS16(gb1 + ko, lb1[buf ^ 1]);
        }
        const ushort_t* as = &As[buf][0];
        const ushort_t* bs = &Bs[buf][0];
        #pragma unroll
        for (int kb = 0; kb < 2; kb++) {
            short8 af[2], bfr[2];
            #pragma unroll
            for (int t = 0; t < 2; t++) {
                int m = ma0 + t * 16 + fm;
                int pa = (kb * 4 + q) ^ (m & 7);
                af[t] = *(const short8*)&as[m * 64 + pa * 8];
                int n = na0 + t * 16 + fm;
                int pb = (kb * 4 + q) ^ (n & 7);
                bfr[t] = *(const short8*)&bs[n * 64 + pb * 8];
            }
            #pragma unroll
            for (int i = 0; i < 2; i++)
                #pragma unroll
                for (int j = 0; j < 2; j++)
                    acc[i][j] = __builtin_amdgcn_mfma_f32_16x16x32_bf16(af[i], bfr[j], acc[i][j], 0, 0, 0);
        }
    }
    #pragma unroll
    for (int i = 0; i < 2; i++)
        #pragma unroll
        for (int j = 0; j < 2; j++) {
            int rowg = m0 + ma0 + i * 16 + q * 4;
            int col = n0 + na0 + j * 16 + fm;
            #pragma unroll
            for (int t = 0; t < 4; t++) {
                float val = acc[i][j][t];
                if (MODE == 0) {
                    ((float*)Cv)[(size_t)(rowg + t) * ldc + col] = val;
                } else if (MODE == 1) {
                    ((ushort_t*)Cv)[(size_t)(rowg + t) * ldc + col] = f2bf(val);
                } else {
                    int m = rowg + t;
                    int b = m >> 7, p = m & 127;
                    ((float*)Cv)[(size_t)(b * S_ + CSTART + p) * H_ + col] = val;
                    if (p == 0) rbuf[b * H_ + col] = val;
                }
            }
        }
}

// ---------- MFMA attention: block = (b,h), 8 waves; softmax in registers ----------
// QKV is bf16 [512][3072]. LDS: Qs/Ksh[128][72] bf16 (overlaid by Pb[128][136]),
// linv[128] f32, amk[128] int, Vt[64][136] bf16. 55296 B.
__global__ __launch_bounds__(512) void attn(const ushort_t* __restrict__ QKV,
                                            const int* __restrict__ amask,
                                            ushort_t* __restrict__ AO) {
    __shared__ __align__(16) char smem[55296];
    ushort_t* Qs  = (ushort_t*)(smem);             // stride 72
    ushort_t* Ksh = (ushort_t*)(smem + 18432);     // stride 72
    ushort_t* Pb  = (ushort_t*)(smem);             // overlay, stride 136
    float*    linv = (float*)(smem + 36864);
    int*      amk  = (int*)(smem + 37376);
    ushort_t* Vt   = (ushort_t*)(smem + 37888);    // stride 136

    int b = blockIdx.x >> 4;
    int h = blockIdx.x & 15;
    int tid = threadIdx.x;
    {
        int r = tid >> 2, ch = tid & 3;   // r 0..127, 16 dims per thread
        const ushort_t* base = QKV + (size_t)(b * CTX + r) * 3072 + h * 64 + ch * 16;
        uint4 q0 = *(const uint4*)(base);
        uint4 q1 = *(const uint4*)(base + 8);
        *(uint4*)(Qs + r * 72 + ch * 16)     = q0;
        *(uint4*)(Qs + r * 72 + ch * 16 + 8) = q1;
        uint4 k0 = *(const uint4*)(base + 1024);
        uint4 k1 = *(const uint4*)(base + 1024 + 8);
        *(uint4*)(Ksh + r * 72 + ch * 16)     = k0;
        *(uint4*)(Ksh + r * 72 + ch * 16 + 8) = k1;
        union { uint4 u4[2]; ushort_t us[16]; } vv;
        vv.u4[0] = *(const uint4*)(base + 2048);
        vv.u4[1] = *(const uint4*)(base + 2048 + 8);
        #pragma unroll
        for (int i = 0; i < 16; i++)
            Vt[(ch * 16 + i) * 136 + r] = vv.us[i];    // Vt[d][c]
        if (tid < 128) amk[tid] = amask[b * S_ + CSTART + tid];
    }
    __syncthreads();

    int w = tid >> 6, lane = tid & 63;
    int qt = w;
    int fm = lane & 15, quad = lane >> 4;

    // ---- S = Q K^T (causal tiles only) ----
    short8 af[2];
    #pragma unroll
    for (int kb = 0; kb < 2; kb++)
        af[kb] = *(const short8*)(Qs + (qt * 16 + fm) * 72 + kb * 32 + quad * 8);
    floatx4 acc[8] = {};
    for (int ct = 0; ct <= qt; ct++) {
        #pragma unroll
        for (int kb = 0; kb < 2; kb++) {
            short8 bfr = *(const short8*)(Ksh + (ct * 16 + fm) * 72 + kb * 32 + quad * 8);
            acc[ct] = __builtin_amdgcn_mfma_f32_16x16x32_bf16(af[kb], bfr, acc[ct], 0, 0, 0);
        }
    }
    // ---- softmax in registers ----
    int myamk[8];
    #pragma unroll
    for (int ct = 0; ct < 8; ct++) myamk[ct] = amk[ct * 16 + fm];
    float ls[4];
    #pragma unroll
    for (int t = 0; t < 4; t++) {
        int row = qt * 16 + quad * 4 + t;
        float m = -INFINITY;
        #pragma unroll
        for (int ct = 0; ct < 8; ct++) {
            int col = ct * 16 + fm;
            float s = acc[ct][t] * 0.125f;
            bool valid = (ct <= qt) && (col <= row) && (myamk[ct] != 0);
            if (valid) m = fmaxf(m, s);
        }
        #pragma unroll
        for (int off = 8; off >= 1; off >>= 1) m = fmaxf(m, __shfl_xor(m, off, 64));
        float l = 0.f;
        #pragma unroll
        for (int ct = 0; ct < 8; ct++) {
            int col = ct * 16 + fm;
            float s = acc[ct][t] * 0.125f;
            bool valid = (ct <= qt) && (col <= row) && (myamk[ct] != 0);
            float p = valid ? __expf(s - m) : 0.f;
            acc[ct][t] = p;
            l += p;
        }
        #pragma unroll
        for (int off = 8; off >= 1; off >>= 1) l += __shfl_xor(l, off, 64);
        ls[t] = l;
    }
    __syncthreads();   // QK^T LDS reads done; Pb overlays Qs/Ksh
    #pragma unroll
    for (int t = 0; t < 4; t++) {
        int row = qt * 16 + quad * 4 + t;
        #pragma unroll
        for (int ct = 0; ct < 8; ct++)
            Pb[row * 136 + ct * 16 + fm] = f2bf(acc[ct][t]);
        if (fm == 0) linv[row] = 1.f / ls[t];
    }
    // ---- O = P V ----
    int kmax = (qt >> 1) + 1;
    floatx4 oacc[4] = {};
    for (int kb = 0; kb < kmax; kb++) {
        short8 paf = *(const short8*)(Pb + (qt * 16 + fm) * 136 + kb * 32 + quad * 8);
        #pragma unroll
        for (int dt = 0; dt < 4; dt++) {
            short8 vbf = *(const short8*)(Vt + (dt * 16 + fm) * 136 + kb * 32 + quad * 8);
            oacc[dt] = __builtin_amdgcn_mfma_f32_16x16x32_bf16(paf, vbf, oacc[dt], 0, 0, 0);
        }
    }
    #pragma unroll
    for (int t = 0; t < 4; t++) {
        int row = qt * 16 + quad * 4 + t;
        float inv = linv[row];
        #pragma unroll
        for (int dt = 0; dt < 4; dt++)
            AO[(size_t)(b * CTX + row) * H_ + h * 64 + dt * 16 + fm] = f2bf(oacc[dt][t] * inv);
    }
}

// ---------- broadcast rows p < CSTART from rbuf ----------
__global__ __launch_bounds__(256) void write_bcast(const float* __restrict__ rbuf,
                                                   float* __restrict__ out) {
    size_t idx = (size_t)blockIdx.x * 256 + threadIdx.x;
    int b   = (int)(idx / (CSTART * 256));
    int rem = (int)(idx % (CSTART * 256));
    int p   = rem >> 8;
    int c4  = rem & 255;
    float4 v = ((const float4*)(rbuf + (size_t)b * H_))[c4];
    ((float4*)(out + (size_t)(b * S_ + p) * H_))[c4] = v;
}

extern "C" void kernel_launch(void* const* d_in, const int* in_sizes, int n_in,
                              void* d_out, int out_size, void* d_ws, size_t ws_size,
                              hipStream_t stream) {
    const float* inputs = (const float*)d_in[0];
    const int*   amask  = (const int*)d_in[1];
    const float* Wq     = (const float*)d_in[2];
    const float* Wk     = (const float*)d_in[3];
    const float* Wv     = (const float*)d_in[4];
    const float* Wo     = (const float*)d_in[5];
    float* out = (float*)d_out;

    char* ws = (char*)d_ws;
    ushort_t* Xs   = (ushort_t*)(ws);                 // 1 MB
    ushort_t* Wbf  = (ushort_t*)(ws + (1u << 20));    // 8 MB (Wq|Wk|Wv|Wo)
    ushort_t* QKV  = (ushort_t*)(ws + (9u << 20));    // 3 MB bf16 [512][3072]
    ushort_t* AObf = (ushort_t*)(ws + (13u << 20));   // 1 MB [512][1024]
    float*    rbuf = (float*)(ws + (14u << 20));      // 16 KB [4][1024]

    prep<<<2304, 256, 0, stream>>>(inputs, Wq, Wk, Wv, Wo, Wbf, Xs);

    dim3 gq(3072 / 64, 512 / 64);
    gemm_t<1><<<gq, 256, 0, stream>>>(Xs, Wbf, (void*)QKV, nullptr, 3072);

    attn<<<64, 512, 0, stream>>>(QKV, amask, AObf);

    dim3 go(1024 / 64, 512 / 64);
    gemm_t<2><<<go, 256, 0, stream>>>(AObf, Wbf + (size_t)3072 * 1024, (void*)out, rbuf, H_);

    write_bcast<<<(B_ * CSTART * 256) / 256, 256, 0, stream>>>(rbuf, out);
}

// Round 6
// 153.251 us; speedup vs baseline: 1.0402x; 1.0402x over previous
//
#include <hip/hip_runtime.h>
#include <math.h>

#define B_ 4
#define S_ 4096
#define H_ 1024
#define NH 16
#define DH 64
#define CTX 128
#define CSTART (S_ - CTX)   // 3968
#define KDIM 1024
#define KH 512              // split-K half

typedef __attribute__((ext_vector_type(8))) short short8;
typedef __attribute__((ext_vector_type(4))) float floatx4;
typedef unsigned short ushort_t;

__device__ inline unsigned short f2bf(float x) {
    union { float f; unsigned u; } v; v.f = x;
    unsigned r = v.u + 0x7fffu + ((v.u >> 16) & 1u);   // RNE
    return (unsigned short)(r >> 16);
}

__device__ inline uint4 pack8(float4 a, float4 b) {
    union { unsigned short us[8]; uint4 u4; } p;
    p.us[0]=f2bf(a.x); p.us[1]=f2bf(a.y); p.us[2]=f2bf(a.z); p.us[3]=f2bf(a.w);
    p.us[4]=f2bf(b.x); p.us[5]=f2bf(b.y); p.us[6]=f2bf(b.z); p.us[7]=f2bf(b.w);
    return p.u4;
}

__device__ inline float4 add4(float4 a, float4 b) {
    float4 r; r.x=a.x+b.x; r.y=a.y+b.y; r.z=a.z+b.z; r.w=a.w+b.w; return r;
}

#define GLOAD_LDS16(g, l) \
    __builtin_amdgcn_global_load_lds((__attribute__((address_space(1))) const void*)(g), \
                                     (__attribute__((address_space(3))) void*)(l), 16, 0, 0)

// ---------- prep: conv weights (blocks 0..2047) + gather x slice (2048..2303) ----------
__global__ __launch_bounds__(256) void prep(const float* __restrict__ in,
                                            const float* __restrict__ Wq, const float* __restrict__ Wk,
                                            const float* __restrict__ Wv, const float* __restrict__ Wo,
                                            ushort_t* __restrict__ Wbf, ushort_t* __restrict__ Xs) {
    int bx = blockIdx.x;
    if (bx < 2048) {
        size_t idx = (size_t)bx * 256 + threadIdx.x;
        size_t e = idx * 8;
        int wsel = (int)(e >> 20);
        size_t off = e & 1048575;
        const float* src = wsel == 0 ? Wq : wsel == 1 ? Wk : wsel == 2 ? Wv : Wo;
        const float4* s4 = (const float4*)(src + off);
        *(uint4*)(Wbf + e) = pack8(s4[0], s4[1]);
    } else {
        int idx = (bx - 2048) * 256 + threadIdx.x;
        int e = idx * 8;
        int m = e >> 10;
        int col = e & 1023;
        int b = m >> 7, i = m & 127;
        const float4* s4 = (const float4*)(in + (size_t)(b * S_ + CSTART + i) * H_ + col);
        *(uint4*)(Xs + e) = pack8(s4[0], s4[1]);
    }
}

// ---------- split-K bf16 MFMA GEMM: P[ks][512][N] = A[:,ks*512+..] @ W[:,ks*512+..]^T ----------
// Single-buffered (r4-proven), BK=64, chunk-swizzle p = g ^ (row&7).
__global__ __launch_bounds__(256) void gemm_part(const ushort_t* __restrict__ A,
                                                 const ushort_t* __restrict__ W,
                                                 float* __restrict__ P, int N) {
    __shared__ ushort_t As[64][64];
    __shared__ ushort_t Bs[64][64];
    int tid = threadIdx.x;
    int lane = tid & 63, w = tid >> 6;
    int m0 = blockIdx.y * 64, n0 = blockIdx.x * 64;
    int ks = blockIdx.z;
    int f0 = tid, f1 = tid + 256;
    int r0 = f0 >> 3, g0 = (f0 & 7) ^ (r0 & 7);
    int r1 = f1 >> 3, g1 = (f1 & 7) ^ (r1 & 7);
    const ushort_t* ga0 = A + (size_t)(m0 + r0) * KDIM + ks * KH + g0 * 8;
    const ushort_t* ga1 = A + (size_t)(m0 + r1) * KDIM + ks * KH + g1 * 8;
    const ushort_t* gb0 = W + (size_t)(n0 + r0) * KDIM + ks * KH + g0 * 8;
    const ushort_t* gb1 = W + (size_t)(n0 + r1) * KDIM + ks * KH + g1 * 8;
    char* la0 = (char*)As + f0 * 16;
    char* la1 = (char*)As + f1 * 16;
    char* lb0 = (char*)Bs + f0 * 16;
    char* lb1 = (char*)Bs + f1 * 16;
    int fm = lane & 15, q = lane >> 4;
    int wr = w >> 1, wc = w & 1;
    int ma0 = wr * 32, na0 = wc * 32;
    floatx4 acc[2][2] = {};
    for (int k0 = 0; k0 < KH; k0 += 64) {
        GLOAD_LDS16(ga0 + k0, la0);
        GLOAD_LDS16(ga1 + k0, la1);
        GLOAD_LDS16(gb0 + k0, lb0);
        GLOAD_LDS16(gb1 + k0, lb1);
        __syncthreads();
        #pragma unroll
        for (int kb = 0; kb < 2; kb++) {
            short8 af[2], bfr[2];
            #pragma unroll
            for (int t = 0; t < 2; t++) {
                int m = ma0 + t * 16 + fm;
                int pa = (kb * 4 + q) ^ (m & 7);
                af[t] = *(const short8*)&As[m][pa * 8];
                int n = na0 + t * 16 + fm;
                int pb = (kb * 4 + q) ^ (n & 7);
                bfr[t] = *(const short8*)&Bs[n][pb * 8];
            }
            #pragma unroll
            for (int i = 0; i < 2; i++)
                #pragma unroll
                for (int j = 0; j < 2; j++)
                    acc[i][j] = __builtin_amdgcn_mfma_f32_16x16x32_bf16(af[i], bfr[j], acc[i][j], 0, 0, 0);
        }
        __syncthreads();
    }
    float* outp = P + (size_t)ks * 512 * N;
    #pragma unroll
    for (int i = 0; i < 2; i++)
        #pragma unroll
        for (int j = 0; j < 2; j++) {
            int row = m0 + ma0 + i * 16 + q * 4;
            int col = n0 + na0 + j * 16 + fm;
            #pragma unroll
            for (int t = 0; t < 4; t++)
                outp[(size_t)(row + t) * N + col] = acc[i][j][t];
        }
}

// ---------- MFMA attention; stages Q/K/V = partial0 + partial1 (fp32) ----------
// LDS: Qs/Ksh[128][72] bf16 (overlaid by Pb[128][136]), linv[128] f32,
// amk[128] int, Vt[64][136] bf16. 55296 B.
__global__ __launch_bounds__(512) void attn(const float* __restrict__ Pq,   // [2][512][3072]
                                            const int* __restrict__ amask,
                                            ushort_t* __restrict__ AO) {
    __shared__ __align__(16) char smem[55296];
    ushort_t* Qs  = (ushort_t*)(smem);             // stride 72
    ushort_t* Ksh = (ushort_t*)(smem + 18432);     // stride 72
    ushort_t* Pb  = (ushort_t*)(smem);             // overlay, stride 136
    float*    linv = (float*)(smem + 36864);
    int*      amk  = (int*)(smem + 37376);
    ushort_t* Vt   = (ushort_t*)(smem + 37888);    // stride 136

    int b = blockIdx.x >> 4;
    int h = blockIdx.x & 15;
    int tid = threadIdx.x;
    {
        int r = tid >> 2, ch = tid & 3;   // r 0..127, 16 dims per thread
        size_t base = (size_t)(b * CTX + r) * 3072 + h * 64 + ch * 16;
        const float4* p0 = (const float4*)(Pq + base);
        const float4* p1 = (const float4*)(Pq + (size_t)512 * 3072 + base);
        // Q
        float4 a0 = add4(p0[0], p1[0]), a1 = add4(p0[1], p1[1]);
        float4 a2 = add4(p0[2], p1[2]), a3 = add4(p0[3], p1[3]);
        *(uint4*)(Qs + r * 72 + ch * 16)     = pack8(a0, a1);
        *(uint4*)(Qs + r * 72 + ch * 16 + 8) = pack8(a2, a3);
        // K (+1024 floats = +256 float4)
        a0 = add4(p0[256], p1[256]); a1 = add4(p0[257], p1[257]);
        a2 = add4(p0[258], p1[258]); a3 = add4(p0[259], p1[259]);
        *(uint4*)(Ksh + r * 72 + ch * 16)     = pack8(a0, a1);
        *(uint4*)(Ksh + r * 72 + ch * 16 + 8) = pack8(a2, a3);
        // V (+2048 floats = +512 float4), transposed
        float vv[16];
        #pragma unroll
        for (int c4 = 0; c4 < 4; c4++) {
            float4 s = add4(p0[512 + c4], p1[512 + c4]);
            vv[c4*4+0]=s.x; vv[c4*4+1]=s.y; vv[c4*4+2]=s.z; vv[c4*4+3]=s.w;
        }
        #pragma unroll
        for (int i = 0; i < 16; i++)
            Vt[(ch * 16 + i) * 136 + r] = f2bf(vv[i]);   // Vt[d][c]
        if (tid < 128) amk[tid] = amask[b * S_ + CSTART + tid];
    }
    __syncthreads();

    int w = tid >> 6, lane = tid & 63;
    int qt = w;
    int fm = lane & 15, quad = lane >> 4;

    // ---- S = Q K^T (causal tiles only) ----
    short8 af[2];
    #pragma unroll
    for (int kb = 0; kb < 2; kb++)
        af[kb] = *(const short8*)(Qs + (qt * 16 + fm) * 72 + kb * 32 + quad * 8);
    floatx4 acc[8] = {};
    for (int ct = 0; ct <= qt; ct++) {
        #pragma unroll
        for (int kb = 0; kb < 2; kb++) {
            short8 bfr = *(const short8*)(Ksh + (ct * 16 + fm) * 72 + kb * 32 + quad * 8);
            acc[ct] = __builtin_amdgcn_mfma_f32_16x16x32_bf16(af[kb], bfr, acc[ct], 0, 0, 0);
        }
    }
    // ---- softmax in registers ----
    int myamk[8];
    #pragma unroll
    for (int ct = 0; ct < 8; ct++) myamk[ct] = amk[ct * 16 + fm];
    float ls[4];
    #pragma unroll
    for (int t = 0; t < 4; t++) {
        int row = qt * 16 + quad * 4 + t;
        float m = -INFINITY;
        #pragma unroll
        for (int ct = 0; ct < 8; ct++) {
            int col = ct * 16 + fm;
            float s = acc[ct][t] * 0.125f;
            bool valid = (ct <= qt) && (col <= row) && (myamk[ct] != 0);
            if (valid) m = fmaxf(m, s);
        }
        #pragma unroll
        for (int off = 8; off >= 1; off >>= 1) m = fmaxf(m, __shfl_xor(m, off, 64));
        float l = 0.f;
        #pragma unroll
        for (int ct = 0; ct < 8; ct++) {
            int col = ct * 16 + fm;
            float s = acc[ct][t] * 0.125f;
            bool valid = (ct <= qt) && (col <= row) && (myamk[ct] != 0);
            float p = valid ? __expf(s - m) : 0.f;
            acc[ct][t] = p;
            l += p;
        }
        #pragma unroll
        for (int off = 8; off >= 1; off >>= 1) l += __shfl_xor(l, off, 64);
        ls[t] = l;
    }
    __syncthreads();   // QK^T LDS reads done; Pb overlays Qs/Ksh
    #pragma unroll
    for (int t = 0; t < 4; t++) {
        int row = qt * 16 + quad * 4 + t;
        #pragma unroll
        for (int ct = 0; ct < 8; ct++)
            Pb[row * 136 + ct * 16 + fm] = f2bf(acc[ct][t]);
        if (fm == 0) linv[row] = 1.f / ls[t];
    }
    // ---- O = P V ----
    int kmax = (qt >> 1) + 1;
    floatx4 oacc[4] = {};
    for (int kb = 0; kb < kmax; kb++) {
        short8 paf = *(const short8*)(Pb + (qt * 16 + fm) * 136 + kb * 32 + quad * 8);
        #pragma unroll
        for (int dt = 0; dt < 4; dt++) {
            short8 vbf = *(const short8*)(Vt + (dt * 16 + fm) * 136 + kb * 32 + quad * 8);
            oacc[dt] = __builtin_amdgcn_mfma_f32_16x16x32_bf16(paf, vbf, oacc[dt], 0, 0, 0);
        }
    }
    #pragma unroll
    for (int t = 0; t < 4; t++) {
        int row = qt * 16 + quad * 4 + t;
        float inv = linv[row];
        #pragma unroll
        for (int dt = 0; dt < 4; dt++)
            AO[(size_t)(b * CTX + row) * H_ + h * 64 + dt * 16 + fm] = f2bf(oacc[dt][t] * inv);
    }
}

// ---------- assemble: out = sum of O-partials, broadcast rows for p < CSTART ----------
__global__ __launch_bounds__(256) void assemble(const float* __restrict__ Po,  // [2][512][1024]
                                                float* __restrict__ out) {
    size_t idx = (size_t)blockIdx.x * 256 + threadIdx.x;   // float4 index, 4.19M
    int row = (int)(idx >> 8);
    int c4  = (int)(idx & 255);
    int b = row >> 12;
    int p = row & 4095;
    int lr = (p < CSTART) ? 0 : (p - CSTART);              // row 0 == q=0 == broadcast row
    size_t o = (size_t)(b * CTX + lr) * H_ + c4 * 4;
    float4 v0 = *(const float4*)(Po + o);
    float4 v1 = *(const float4*)(Po + (size_t)512 * H_ + o);
    ((float4*)out)[idx] = add4(v0, v1);
}

extern "C" void kernel_launch(void* const* d_in, const int* in_sizes, int n_in,
                              void* d_out, int out_size, void* d_ws, size_t ws_size,
                              hipStream_t stream) {
    const float* inputs = (const float*)d_in[0];
    const int*   amask  = (const int*)d_in[1];
    const float* Wq     = (const float*)d_in[2];
    const float* Wk     = (const float*)d_in[3];
    const float* Wv     = (const float*)d_in[4];
    const float* Wo     = (const float*)d_in[5];
    float* out = (float*)d_out;

    char* ws = (char*)d_ws;
    ushort_t* Xs   = (ushort_t*)(ws);                 // 1 MB
    ushort_t* Wbf  = (ushort_t*)(ws + (1u << 20));    // 8 MB (Wq|Wk|Wv|Wo)
    float*    Pq   = (float*)(ws + (9u << 20));       // 12.6 MB [2][512][3072] fp32
    ushort_t* AObf = (ushort_t*)(ws + (23u << 20));   // 1 MB [512][1024] bf16
    float*    Po   = (float*)(ws + (24u << 20));      // 4 MB [2][512][1024] fp32

    prep<<<2304, 256, 0, stream>>>(inputs, Wq, Wk, Wv, Wo, Wbf, Xs);

    dim3 gq(3072 / 64, 512 / 64, 2);
    gemm_part<<<gq, 256, 0, stream>>>(Xs, Wbf, Pq, 3072);

    attn<<<64, 512, 0, stream>>>(Pq, amask, AObf);

    dim3 go(1024 / 64, 512 / 64, 2);
    gemm_part<<<go, 256, 0, stream>>>(AObf, Wbf + (size_t)3072 * 1024, Po, 1024);

    assemble<<<16384, 256, 0, stream>>>(Po, out);
}

// Round 7
// 151.372 us; speedup vs baseline: 1.0531x; 1.0124x over previous
//
#include <hip/hip_runtime.h>
#include <math.h>

#define B_ 4
#define S_ 4096
#define H_ 1024
#define NH 16
#define DH 64
#define CTX 128
#define CSTART (S_ - CTX)   // 3968
#define KDIM 1024
#define KH 512              // split-K half

typedef __attribute__((ext_vector_type(8))) short short8;
typedef __attribute__((ext_vector_type(4))) float floatx4;
typedef unsigned short ushort_t;

__device__ inline unsigned short f2bf(float x) {
    union { float f; unsigned u; } v; v.f = x;
    unsigned r = v.u + 0x7fffu + ((v.u >> 16) & 1u);   // RNE
    return (unsigned short)(r >> 16);
}

__device__ inline uint4 pack8(float4 a, float4 b) {
    union { unsigned short us[8]; uint4 u4; } p;
    p.us[0]=f2bf(a.x); p.us[1]=f2bf(a.y); p.us[2]=f2bf(a.z); p.us[3]=f2bf(a.w);
    p.us[4]=f2bf(b.x); p.us[5]=f2bf(b.y); p.us[6]=f2bf(b.z); p.us[7]=f2bf(b.w);
    return p.u4;
}

__device__ inline float4 add4(float4 a, float4 b) {
    float4 r; r.x=a.x+b.x; r.y=a.y+b.y; r.z=a.z+b.z; r.w=a.w+b.w; return r;
}

#define GLOAD_LDS16(g, l) \
    __builtin_amdgcn_global_load_lds((__attribute__((address_space(1))) const void*)(g), \
                                     (__attribute__((address_space(3))) void*)(l), 16, 0, 0)

// ---------- prep: conv weights (blocks 0..2047) + gather x slice (2048..2303) ----------
__global__ __launch_bounds__(256) void prep(const float* __restrict__ in,
                                            const float* __restrict__ Wq, const float* __restrict__ Wk,
                                            const float* __restrict__ Wv, const float* __restrict__ Wo,
                                            ushort_t* __restrict__ Wbf, ushort_t* __restrict__ Xs) {
    int bx = blockIdx.x;
    if (bx < 2048) {
        size_t idx = (size_t)bx * 256 + threadIdx.x;
        size_t e = idx * 8;
        int wsel = (int)(e >> 20);
        size_t off = e & 1048575;
        const float* src = wsel == 0 ? Wq : wsel == 1 ? Wk : wsel == 2 ? Wv : Wo;
        const float4* s4 = (const float4*)(src + off);
        *(uint4*)(Wbf + e) = pack8(s4[0], s4[1]);
    } else {
        int idx = (bx - 2048) * 256 + threadIdx.x;
        int e = idx * 8;
        int m = e >> 10;
        int col = e & 1023;
        int b = m >> 7, i = m & 127;
        const float4* s4 = (const float4*)(in + (size_t)(b * S_ + CSTART + i) * H_ + col);
        *(uint4*)(Xs + e) = pack8(s4[0], s4[1]);
    }
}

// ---------- split-K bf16 MFMA GEMM: P[ks][512][N] = A[:,ks*512+..] @ W[:,ks*512+..]^T ----------
__global__ __launch_bounds__(256) void gemm_part(const ushort_t* __restrict__ A,
                                                 const ushort_t* __restrict__ W,
                                                 float* __restrict__ P, int N) {
    __shared__ ushort_t As[64][64];
    __shared__ ushort_t Bs[64][64];
    int tid = threadIdx.x;
    int lane = tid & 63, w = tid >> 6;
    int m0 = blockIdx.y * 64, n0 = blockIdx.x * 64;
    int ks = blockIdx.z;
    int f0 = tid, f1 = tid + 256;
    int r0 = f0 >> 3, g0 = (f0 & 7) ^ (r0 & 7);
    int r1 = f1 >> 3, g1 = (f1 & 7) ^ (r1 & 7);
    const ushort_t* ga0 = A + (size_t)(m0 + r0) * KDIM + ks * KH + g0 * 8;
    const ushort_t* ga1 = A + (size_t)(m0 + r1) * KDIM + ks * KH + g1 * 8;
    const ushort_t* gb0 = W + (size_t)(n0 + r0) * KDIM + ks * KH + g0 * 8;
    const ushort_t* gb1 = W + (size_t)(n0 + r1) * KDIM + ks * KH + g1 * 8;
    char* la0 = (char*)As + f0 * 16;
    char* la1 = (char*)As + f1 * 16;
    char* lb0 = (char*)Bs + f0 * 16;
    char* lb1 = (char*)Bs + f1 * 16;
    int fm = lane & 15, q = lane >> 4;
    int wr = w >> 1, wc = w & 1;
    int ma0 = wr * 32, na0 = wc * 32;
    floatx4 acc[2][2] = {};
    for (int k0 = 0; k0 < KH; k0 += 64) {
        GLOAD_LDS16(ga0 + k0, la0);
        GLOAD_LDS16(ga1 + k0, la1);
        GLOAD_LDS16(gb0 + k0, lb0);
        GLOAD_LDS16(gb1 + k0, lb1);
        __syncthreads();
        #pragma unroll
        for (int kb = 0; kb < 2; kb++) {
            short8 af[2], bfr[2];
            #pragma unroll
            for (int t = 0; t < 2; t++) {
                int m = ma0 + t * 16 + fm;
                int pa = (kb * 4 + q) ^ (m & 7);
                af[t] = *(const short8*)&As[m][pa * 8];
                int n = na0 + t * 16 + fm;
                int pb = (kb * 4 + q) ^ (n & 7);
                bfr[t] = *(const short8*)&Bs[n][pb * 8];
            }
            #pragma unroll
            for (int i = 0; i < 2; i++)
                #pragma unroll
                for (int j = 0; j < 2; j++)
                    acc[i][j] = __builtin_amdgcn_mfma_f32_16x16x32_bf16(af[i], bfr[j], acc[i][j], 0, 0, 0);
        }
        __syncthreads();
    }
    float* outp = P + (size_t)ks * 512 * N;
    #pragma unroll
    for (int i = 0; i < 2; i++)
        #pragma unroll
        for (int j = 0; j < 2; j++) {
            int row = m0 + ma0 + i * 16 + q * 4;
            int col = n0 + na0 + j * 16 + fm;
            #pragma unroll
            for (int t = 0; t < 4; t++)
                outp[(size_t)(row + t) * N + col] = acc[i][j][t];
        }
}

// ---------- MFMA attention, query-half split: block = (b, h, half), 256 threads ----------
// Stages Q/K/V = partial0 + partial1 (fp32 adds). half=0 handles q rows 0..63
// (K/V rows 0..63 only, short causal loop); half=1 handles q rows 64..127 (full K/V).
// LDS: Qs[64][72], Ksh[128][72] bf16 (overlaid by Pb[64][136]), linv[64] f32,
// amk[128] int, Vt[64][136] bf16 (cols = ctx pos). 45.8 KB.
__global__ __launch_bounds__(256) void attn(const float* __restrict__ Pq,   // [2][512][3072]
                                            const int* __restrict__ amask,
                                            ushort_t* __restrict__ AO) {
    __shared__ __align__(16) char smem[46080];
    ushort_t* Qs   = (ushort_t*)(smem);             // [64][72]
    ushort_t* Ksh  = (ushort_t*)(smem + 9216);      // [128][72]
    ushort_t* Pb   = (ushort_t*)(smem);             // overlay, [64 local rows][136]
    float*    linv = (float*)(smem + 27648);        // [64]
    int*      amk  = (int*)(smem + 27904);          // [128]
    ushort_t* Vt   = (ushort_t*)(smem + 28416);     // [64 dims][136 ctx]

    int gid = blockIdx.x;
    int b = gid >> 5, h = (gid >> 1) & 15, half = gid & 1;
    int tid = threadIdx.x;
    int cmax = half ? CTX : 64;                     // context rows this block needs
    {
        int r = tid >> 2, ch = tid & 3;             // 16 dims per thread
        // Q: local row r -> global q row half*64 + r
        size_t qb = (size_t)(b * CTX + half * 64 + r) * 3072 + h * 64 + ch * 16;
        const float4* q0 = (const float4*)(Pq + qb);
        const float4* q1 = (const float4*)(Pq + (size_t)512 * 3072 + qb);
        float4 a0 = add4(q0[0], q1[0]), a1 = add4(q0[1], q1[1]);
        float4 a2 = add4(q0[2], q1[2]), a3 = add4(q0[3], q1[3]);
        *(uint4*)(Qs + r * 72 + ch * 16)     = pack8(a0, a1);
        *(uint4*)(Qs + r * 72 + ch * 16 + 8) = pack8(a2, a3);
        // K and V (transposed), rows 0..cmax-1
        for (int idx = tid; idx < cmax * 4; idx += 256) {
            int kr = idx >> 2, kch = idx & 3;
            size_t base = (size_t)(b * CTX + kr) * 3072 + h * 64 + kch * 16;
            const float4* p0 = (const float4*)(Pq + base);
            const float4* p1 = (const float4*)(Pq + (size_t)512 * 3072 + base);
            float4 k0 = add4(p0[256], p1[256]), k1 = add4(p0[257], p1[257]);
            float4 k2 = add4(p0[258], p1[258]), k3 = add4(p0[259], p1[259]);
            *(uint4*)(Ksh + kr * 72 + kch * 16)     = pack8(k0, k1);
            *(uint4*)(Ksh + kr * 72 + kch * 16 + 8) = pack8(k2, k3);
            float vv[16];
            #pragma unroll
            for (int c4 = 0; c4 < 4; c4++) {
                float4 s = add4(p0[512 + c4], p1[512 + c4]);
                vv[c4*4+0]=s.x; vv[c4*4+1]=s.y; vv[c4*4+2]=s.z; vv[c4*4+3]=s.w;
            }
            #pragma unroll
            for (int i = 0; i < 16; i++)
                Vt[(kch * 16 + i) * 136 + kr] = f2bf(vv[i]);   // Vt[d][ctx]
        }
        if (tid < 128) amk[tid] = amask[b * S_ + CSTART + tid];
    }
    __syncthreads();

    int w = tid >> 6, lane = tid & 63;
    int qt = half * 4 + w;                 // global 16-row query tile
    int lr0 = w * 16;                      // local Q/P row base
    int fm = lane & 15, quad = lane >> 4;

    // ---- S = Q K^T (causal tiles only) ----
    short8 af[2];
    #pragma unroll
    for (int kb = 0; kb < 2; kb++)
        af[kb] = *(const short8*)(Qs + (lr0 + fm) * 72 + kb * 32 + quad * 8);
    floatx4 acc[8] = {};
    for (int ct = 0; ct <= qt; ct++) {
        #pragma unroll
        for (int kb = 0; kb < 2; kb++) {
            short8 bfr = *(const short8*)(Ksh + (ct * 16 + fm) * 72 + kb * 32 + quad * 8);
            acc[ct] = __builtin_amdgcn_mfma_f32_16x16x32_bf16(af[kb], bfr, acc[ct], 0, 0, 0);
        }
    }
    // ---- softmax in registers ----
    int myamk[8];
    #pragma unroll
    for (int ct = 0; ct < 8; ct++) myamk[ct] = amk[ct * 16 + fm];
    float ls[4];
    #pragma unroll
    for (int t = 0; t < 4; t++) {
        int row = qt * 16 + quad * 4 + t;
        float m = -INFINITY;
        #pragma unroll
        for (int ct = 0; ct < 8; ct++) {
            int col = ct * 16 + fm;
            float s = acc[ct][t] * 0.125f;
            bool valid = (ct <= qt) && (col <= row) && (myamk[ct] != 0);
            if (valid) m = fmaxf(m, s);
        }
        #pragma unroll
        for (int off = 8; off >= 1; off >>= 1) m = fmaxf(m, __shfl_xor(m, off, 64));
        float l = 0.f;
        #pragma unroll
        for (int ct = 0; ct < 8; ct++) {
            int col = ct * 16 + fm;
            float s = acc[ct][t] * 0.125f;
            bool valid = (ct <= qt) && (col <= row) && (myamk[ct] != 0);
            float p = valid ? __expf(s - m) : 0.f;
            acc[ct][t] = p;
            l += p;
        }
        #pragma unroll
        for (int off = 8; off >= 1; off >>= 1) l += __shfl_xor(l, off, 64);
        ls[t] = l;
    }
    __syncthreads();   // QK^T LDS reads done; Pb overlays Qs/Ksh
    #pragma unroll
    for (int t = 0; t < 4; t++) {
        int lrow = lr0 + quad * 4 + t;
        #pragma unroll
        for (int ct = 0; ct < 8; ct++)
            Pb[lrow * 136 + ct * 16 + fm] = f2bf(acc[ct][t]);
        if (fm == 0) linv[lrow] = 1.f / ls[t];
    }
    // ---- O = P V ----
    int kmax = (qt >> 1) + 1;              // 32-wide k blocks
    floatx4 oacc[4] = {};
    for (int kb = 0; kb < kmax; kb++) {
        short8 paf = *(const short8*)(Pb + (lr0 + fm) * 136 + kb * 32 + quad * 8);
        #pragma unroll
        for (int dt = 0; dt < 4; dt++) {
            short8 vbf = *(const short8*)(Vt + (dt * 16 + fm) * 136 + kb * 32 + quad * 8);
            oacc[dt] = __builtin_amdgcn_mfma_f32_16x16x32_bf16(paf, vbf, oacc[dt], 0, 0, 0);
        }
    }
    #pragma unroll
    for (int t = 0; t < 4; t++) {
        int lrow = lr0 + quad * 4 + t;
        int grow = qt * 16 + quad * 4 + t;
        float inv = linv[lrow];
        #pragma unroll
        for (int dt = 0; dt < 4; dt++)
            AO[(size_t)(b * CTX + grow) * H_ + h * 64 + dt * 16 + fm] = f2bf(oacc[dt][t] * inv);
    }
}

// ---------- assemble: out = sum of O-partials, broadcast rows for p < CSTART ----------
__global__ __launch_bounds__(256) void assemble(const float* __restrict__ Po,  // [2][512][1024]
                                                float* __restrict__ out) {
    size_t idx = (size_t)blockIdx.x * 256 + threadIdx.x;   // float4 index, 4.19M
    int row = (int)(idx >> 8);
    int c4  = (int)(idx & 255);
    int b = row >> 12;
    int p = row & 4095;
    int lr = (p < CSTART) ? 0 : (p - CSTART);              // row 0 == q=0 == broadcast row
    size_t o = (size_t)(b * CTX + lr) * H_ + c4 * 4;
    float4 v0 = *(const float4*)(Po + o);
    float4 v1 = *(const float4*)(Po + (size_t)512 * H_ + o);
    ((float4*)out)[idx] = add4(v0, v1);
}

extern "C" void kernel_launch(void* const* d_in, const int* in_sizes, int n_in,
                              void* d_out, int out_size, void* d_ws, size_t ws_size,
                              hipStream_t stream) {
    const float* inputs = (const float*)d_in[0];
    const int*   amask  = (const int*)d_in[1];
    const float* Wq     = (const float*)d_in[2];
    const float* Wk     = (const float*)d_in[3];
    const float* Wv     = (const float*)d_in[4];
    const float* Wo     = (const float*)d_in[5];
    float* out = (float*)d_out;

    char* ws = (char*)d_ws;
    ushort_t* Xs   = (ushort_t*)(ws);                 // 1 MB
    ushort_t* Wbf  = (ushort_t*)(ws + (1u << 20));    // 8 MB (Wq|Wk|Wv|Wo)
    float*    Pq   = (float*)(ws + (9u << 20));       // 12.6 MB [2][512][3072] fp32
    ushort_t* AObf = (ushort_t*)(ws + (23u << 20));   // 1 MB [512][1024] bf16
    float*    Po   = (float*)(ws + (24u << 20));      // 4 MB [2][512][1024] fp32

    prep<<<2304, 256, 0, stream>>>(inputs, Wq, Wk, Wv, Wo, Wbf, Xs);

    dim3 gq(3072 / 64, 512 / 64, 2);
    gemm_part<<<gq, 256, 0, stream>>>(Xs, Wbf, Pq, 3072);

    attn<<<128, 256, 0, stream>>>(Pq, amask, AObf);

    dim3 go(1024 / 64, 512 / 64, 2);
    gemm_part<<<go, 256, 0, stream>>>(AObf, Wbf + (size_t)3072 * 1024, Po, 1024);

    assemble<<<16384, 256, 0, stream>>>(Po, out);
}